// Round 1
// baseline (155.618 us; speedup 1.0000x reference)
//
#include <hip/hip_runtime.h>
#include <stdint.h>

#define BATCH 32
#define NA 8732
#define NC 21
#define SHW 90000
#define MAXGT 64
#define NQ (SHW / 4)          // 22500 pixel-quads per image per channel

// ---- k_seg slab decomposition: 2048 px per block, 2 quads per thread ----
#define SLABQ 512                          // quads per block
#define NSLAB ((NQ + SLABQ - 1) / SLABQ)   // 44 slabs/image
#define NBLK (BATCH * NSLAB)               // 1408 blocks

__constant__ int c_loff[6] = {0, 5776, 7942, 8542, 8692, 8728};
__constant__ int c_lnb[6]  = {4, 6, 6, 6, 4, 4};

__device__ __forceinline__ unsigned f2key(float f) {
    unsigned u = __float_as_uint(f);
    return (u & 0x80000000u) ? ~u : (u | 0x80000000u);
}
__device__ __forceinline__ float key2f(unsigned k) {
    return __uint_as_float((k & 0x80000000u) ? (k ^ 0x80000000u) : ~k);
}

// ============================================================================
// k_front: fused build + cls-CE + hard-negative topk. One block per image.
// Eliminates k_init, global cls_t, and global scores (build-phase anchor
// index a = tid + i*1024 equals cls-phase row index, so the target class
// rides in per-thread registers cvr[9]; topk keys go straight to LDS).
// Per-image partials written non-atomically; k_seg's last block combines.
// ============================================================================
__global__ __launch_bounds__(1024) void k_front(
    const int* __restrict__ idxb, const int* __restrict__ clsb,
    const float* __restrict__ gt, const float* __restrict__ df,
    const float* __restrict__ Loc, const float* __restrict__ Cls,
    const int* __restrict__ mining_p,
    float* __restrict__ loc_i, float* __restrict__ posce_i,
    float* __restrict__ negce_i, int* __restrict__ np_i,
    float* __restrict__ segacc, unsigned* __restrict__ done)
{
    const int b = blockIdx.x;
    const int tid = threadIdx.x;
    if (b == 0 && tid == 0) { *segacc = 0.0f; *done = 0u; }  // consumed only by k_seg (later kernel)

    __shared__ int s_flat[MAXGT];
    __shared__ int s_cls[MAXGT];
    __shared__ float s_delta[MAXGT][4];
    __shared__ int s_nv;
    __shared__ float s_rf[16];
    __shared__ float s_rf2[16];
    __shared__ int s_ri[16];
    __shared__ int s_ri2[16];
    __shared__ int s_pp, s_nn;
    __shared__ unsigned s_keys[NA];     // 34928 B
    __shared__ int s_hist[256];
    __shared__ int s_wsum[4];
    __shared__ int s_selb, s_sele;

    // ---- phase 0: GT entries -> LDS ----
    if (tid < MAXGT) {
        int layer = idxb[(b * MAXGT + tid) * 4 + 1];
        int fpos  = idxb[(b * MAXGT + tid) * 4 + 2];
        int dbox  = idxb[(b * MAXGT + tid) * 4 + 3];
        int fl;
        if (layer == -100) fl = -2;  // terminator sentinel
        else {
            int lc = min(max(layer, 0), 5);
            fl = c_loff[lc] + fpos * c_lnb[lc] + dbox;
        }
        s_flat[tid] = fl;
        s_cls[tid] = clsb[b * MAXGT + tid];
        #pragma unroll
        for (int o = 0; o < 4; o++)
            s_delta[tid][o] = (gt[(b * MAXGT + tid) * 4 + o] - df[(b * MAXGT + tid) * 4 + o]) / 0.1f;
    }
    __syncthreads();
    if (tid == 0) {
        int nvv = MAXGT;
        for (int j = 0; j < MAXGT; j++) if (s_flat[j] == -2) { nvv = j; break; }
        s_nv = nvv;
    }
    __syncthreads();
    const int nv = s_nv;

    int rflat[MAXGT];
    #pragma unroll
    for (int j = 0; j < MAXGT; j++)
        rflat[j] = (j < nv) ? s_flat[j] : -3;

    const int mining = *mining_p;
    const signed char cinit = mining ? (signed char)(-1) : (signed char)0;

    // ---- phase 1: target build (gather, last-write-wins) + loc loss ----
    signed char cvr[9];
    int pos_cnt = 0, neg_cnt = 0;
    float loc_sum = 0.0f;
    #pragma unroll
    for (int i = 0; i < 9; i++) {
        const int a = tid + i * 1024;
        signed char cv = cinit;
        if (a < NA) {
            int best = -1;
            #pragma unroll
            for (int j = 0; j < MAXGT; j++)
                best = (rflat[j] == a) ? j : best;   // last match wins
            if (best >= 0) cv = (signed char)s_cls[best];
            if (cv > 0) {
                pos_cnt++;
                const float4 l4 = *reinterpret_cast<const float4*>(Loc + ((size_t)b * NA + a) * 4);
                float lv[4] = {l4.x, l4.y, l4.z, l4.w};
                #pragma unroll
                for (int o = 0; o < 4; o++) {
                    float d = lv[o] - s_delta[best][o];
                    float ad = fabsf(d);
                    loc_sum += (ad < 1.0f) ? (0.5f * d * d) : (ad - 0.5f);
                }
            } else if (cv == -1) {
                neg_cnt++;
            }
        }
        cvr[i] = cv;
    }

    #pragma unroll
    for (int d = 32; d > 0; d >>= 1) {
        loc_sum += __shfl_down(loc_sum, d);
        pos_cnt += __shfl_down(pos_cnt, d);
        neg_cnt += __shfl_down(neg_cnt, d);
    }
    const int lane = tid & 63, wv = tid >> 6;
    if (lane == 0) { s_rf[wv] = loc_sum; s_ri[wv] = pos_cnt; s_ri2[wv] = neg_cnt; }
    __syncthreads();
    if (tid == 0) {
        float lf = 0.0f; int pp = 0, nn = 0;
        #pragma unroll
        for (int w = 0; w < 16; w++) { lf += s_rf[w]; pp += s_ri[w]; nn += s_ri2[w]; }
        loc_i[b] = lf;
        np_i[b] = pp;
        s_pp = pp; s_nn = nn;
    }
    __syncthreads();

    // ---- phase 2: per-row CE (same arithmetic as previous k_cls) ----
    const float* clsrow = Cls + (size_t)b * NA * NC;
    float pos_ce = 0.0f, neg_ce = 0.0f;
    #pragma unroll
    for (int i = 0; i < 9; i++) {
        const int r = tid + i * 1024;
        if (r < NA) {
            const float* row = clsrow + (size_t)r * NC;
            float f[NC];
            #pragma unroll
            for (int c = 0; c < NC; c++) f[c] = row[c];
            float m = f[0];
            #pragma unroll
            for (int c = 1; c < NC; c++) m = fmaxf(m, f[c]);
            float s = 0.0f;
            #pragma unroll
            for (int c = 0; c < NC; c++) s += __expf(f[c] - m);
            float lse = m + __logf(s);
            int ct = (int)cvr[i];
            int lab = ct > 0 ? ct : 0;
            float xt = f[0];
            #pragma unroll
            for (int c = 1; c < NC; c++) xt = (c == lab) ? f[c] : xt;
            float ce_bg = lse - f[0];
            if (ct > 0) pos_ce += lse - xt;
            if (mining) {
                s_keys[r] = f2key((ct == -1) ? ce_bg : -__builtin_inff());
            } else if (ct <= 0) {
                neg_ce += ce_bg;
            }
        }
    }

    float pc = pos_ce, ncv = neg_ce;
    #pragma unroll
    for (int d = 32; d > 0; d >>= 1) {
        pc += __shfl_down(pc, d);
        ncv += __shfl_down(ncv, d);
    }
    if (lane == 0) { s_rf[wv] = pc; s_rf2[wv] = ncv; }
    __syncthreads();   // also orders s_keys writes before radix reads
    if (tid == 0) {
        float p = 0.0f, n = 0.0f;
        #pragma unroll
        for (int w = 0; w < 16; w++) { p += s_rf[w]; n += s_rf2[w]; }
        posce_i[b] = p;
        if (!mining) negce_i[b] = n;
    }

    // ---- phase 3: exact top-k via 4-round radix select (mining only) ----
    if (mining) {
        const int k = min(3 * s_pp, s_nn);
        if (k <= 0) {
            if (tid == 0) negce_i[b] = 0.0f;
            return;
        }
        unsigned pref = 0u;
        int k_rem = k;
        #pragma unroll
        for (int lvl = 0; lvl < 4; lvl++) {
            const int sh = 24 - lvl * 8;
            if (tid < 256) s_hist[tid] = 0;
            __syncthreads();
            for (int a = tid; a < NA; a += 1024) {
                unsigned key = s_keys[a];
                bool in = (lvl == 0) || ((key >> (sh + 8)) == pref);
                if (in) atomicAdd(&s_hist[(key >> sh) & 0xFF], 1);
            }
            __syncthreads();
            int v = 0, x = 0, b_rev = 0;
            if (tid < 256) {
                b_rev = 255 - tid;
                v = s_hist[b_rev];
                x = v;
                #pragma unroll
                for (int d = 1; d < 64; d <<= 1) {
                    int o = __shfl_up(x, d);
                    if (lane >= d) x += o;
                }
                if (lane == 63) s_wsum[wv] = x;
            }
            __syncthreads();
            if (tid < 256) {
                for (int w = 0; w < wv; w++) x += s_wsum[w];
                if (x >= k_rem && (x - v) < k_rem) { s_selb = b_rev; s_sele = x - v; }
            }
            __syncthreads();
            pref = (pref << 8) | (unsigned)s_selb;
            k_rem -= s_sele;
            __syncthreads();
        }

        float sum_g = 0.0f; int cnt_g = 0;
        for (int a = tid; a < NA; a += 1024) {
            unsigned key = s_keys[a];
            if (key > pref) { sum_g += key2f(key); cnt_g++; }
        }
        #pragma unroll
        for (int d = 32; d > 0; d >>= 1) {
            sum_g += __shfl_down(sum_g, d);
            cnt_g += __shfl_down(cnt_g, d);
        }
        if (lane == 0) { s_rf[wv] = sum_g; s_ri[wv] = cnt_g; }
        __syncthreads();
        if (tid == 0) {
            float sg = 0.0f; int cg = 0;
            #pragma unroll
            for (int w = 0; w < 16; w++) { sg += s_rf[w]; cg += s_ri[w]; }
            negce_i[b] = sg + (float)(k - cg) * key2f(pref);
        }
    }
}

// ============================================================================
// k_seg: streaming seg CE, 3-channel-ahead pipeline (6 seg loads in flight).
// ============================================================================

// Online-LSE update, 1 transcendental per element (bit-identical to 2-exp
// form, verified absmax 0.0 in prior rounds).
__device__ __forceinline__ void upd1(float& m, float& s, float& tg,
                                     int lab, float x, int c) {
    tg = (lab == c) ? x : tg;
    const float d = x - m;
    const float e = __expf(-fabsf(d));
    s = (d > 0.0f) ? fmaf(s, e, 1.0f) : (s + e);
    m = fmaxf(m, x);
}
__device__ __forceinline__ void upd4(float4& m, float4& s, float4& tg,
                                     const int4& lab, const float4& x, int c) {
    upd1(m.x, s.x, tg.x, lab.x, x.x, c);
    upd1(m.y, s.y, tg.y, lab.y, x.y, c);
    upd1(m.z, s.z, tg.z, lab.z, x.z, c);
    upd1(m.w, s.w, tg.w, lab.w, x.w, c);
}

// Inline-asm loads + counted vmcnt: the ONLY way to guarantee in-flight depth
// on HIP (compiler drains loads otherwise — established R3/R8/R9).
#define GLOAD_F4(dst, addr) \
    asm volatile("global_load_dwordx4 %0, %1, off" : "=v"(dst) : "v"(addr))
#define GLOAD_I4(dst, addr) \
    asm volatile("global_load_dwordx4 %0, %1, off" : "=v"(dst) : "v"(addr))
// rule #18: sched_barrier(0) after the wait so VALU consumers can't hoist
// above it (the "memory" clobber does not order register-only consumers).
#define SWAIT(lit) do { \
    asm volatile("s_waitcnt vmcnt(" #lit ")" ::: "memory"); \
    __builtin_amdgcn_sched_barrier(0); } while (0)

__global__ __launch_bounds__(256) void k_seg(
    const float* __restrict__ Seg, const int* __restrict__ slab_lab,
    float* __restrict__ segacc, const int* __restrict__ np_i,
    const float* __restrict__ loc_i, const float* __restrict__ posce_i,
    const float* __restrict__ negce_i, unsigned* __restrict__ done,
    float* __restrict__ out)
{
    __shared__ float s_w[4];
    const int t = threadIdx.x;
    const int img = blockIdx.x / NSLAB;
    const int sl  = blockIdx.x - img * NSLAB;
    const int qbase = sl * SLABQ;
    const int q0 = qbase + t;              // max 43*512+255 = 22271 < NQ: always valid
    const int q1 = qbase + 256 + t;
    const bool vb = (q1 < NQ);
    const int q1s = vb ? q1 : q0;

    const float4* segq = (const float4*)(Seg + (size_t)img * NC * SHW);
    const int4* labq = (const int4*)(slab_lab + (size_t)img * SHW);

    const uint64_t abase = (uint64_t)(segq + q0);
    const uint64_t bbase = (uint64_t)(segq + q1s);
    const uint64_t cstep = (uint64_t)NQ * 16;   // channel stride in bytes

    int4 la, lb;
    float4 A0, A1, A2, B0, B1, B2;

    // issue order: labels (2), then c=0,1,2 pairs -> 8 outstanding
    GLOAD_I4(la, (uint64_t)(labq + q0));
    GLOAD_I4(lb, (uint64_t)(labq + q1s));
    GLOAD_F4(A0, abase);                 GLOAD_F4(B0, bbase);
    GLOAD_F4(A1, abase + cstep);         GLOAD_F4(B1, bbase + cstep);
    GLOAD_F4(A2, abase + 2 * cstep);     GLOAD_F4(B2, bbase + 2 * cstep);

    SWAIT(6);  // labels arrived; 6 seg loads still in flight

    float4 ma, sa, ta, mb, sb, tb;

    #pragma unroll
    for (int c = 0; c < NC; ++c) {
        // steady state keeps 2 channel-pairs in flight; tail drains 2 -> 0
        if (c == NC - 1)      SWAIT(0);
        else if (c == NC - 2) SWAIT(2);
        else                  SWAIT(4);
        const int sl3 = c % 3;
        const float4 xa = (sl3 == 0) ? A0 : ((sl3 == 1) ? A1 : A2);
        const float4 xb = (sl3 == 0) ? B0 : ((sl3 == 1) ? B1 : B2);
        if (c == 0) {
            ma = xa; ta = xa; mb = xb; tb = xb;
            sa = make_float4(1.f, 1.f, 1.f, 1.f);
            sb = make_float4(1.f, 1.f, 1.f, 1.f);
        } else {
            upd4(ma, sa, ta, la, xa, c);
            upd4(mb, sb, tb, lb, xb, c);
        }
        if (c + 3 < NC) {   // reissue this pair's slots for channel c+3
            const uint64_t off = (uint64_t)(c + 3) * cstep;
            if (sl3 == 0)      { GLOAD_F4(A0, abase + off); GLOAD_F4(B0, bbase + off); }
            else if (sl3 == 1) { GLOAD_F4(A1, abase + off); GLOAD_F4(B1, bbase + off); }
            else               { GLOAD_F4(A2, abase + off); GLOAD_F4(B2, bbase + off); }
        }
    }

    float lsum = (ma.x + __logf(sa.x) - ta.x)
               + (ma.y + __logf(sa.y) - ta.y)
               + (ma.z + __logf(sa.z) - ta.z)
               + (ma.w + __logf(sa.w) - ta.w);
    if (vb) {
        lsum += (mb.x + __logf(sb.x) - tb.x)
              + (mb.y + __logf(sb.y) - tb.y)
              + (mb.z + __logf(sb.z) - tb.z)
              + (mb.w + __logf(sb.w) - tb.w);
    }

    #pragma unroll
    for (int d = 32; d > 0; d >>= 1) lsum += __shfl_down(lsum, d);
    const int lane = t & 63, wvv = t >> 6;
    if (lane == 0) s_w[wvv] = lsum;
    __syncthreads();
    if (t == 0) {
        atomicAdd(segacc, s_w[0] + s_w[1] + s_w[2] + s_w[3]);
        __threadfence();
        unsigned old = atomicAdd(done, 1u);
        if (old == gridDim.x - 1) {
            __threadfence();
            int np = 0; float lc = 0.0f, pcs = 0.0f, ncs = 0.0f;
            #pragma unroll
            for (int i = 0; i < BATCH; i++) {
                np += np_i[i]; lc += loc_i[i]; pcs += posce_i[i]; ncs += negce_i[i];
            }
            float npf = (float)(np > 1 ? np : 1);
            out[0] = (pcs + ncs + lc) / npf + (*segacc) / (float)(BATCH * SHW);
        }
    }
}

extern "C" void kernel_launch(void* const* d_in, const int* in_sizes, int n_in,
                              void* d_out, int out_size, void* d_ws, size_t ws_size,
                              hipStream_t stream)
{
    const float* Loc = (const float*)d_in[0];
    const float* Cls = (const float*)d_in[1];
    const float* Seg = (const float*)d_in[2];
    const float* gt  = (const float*)d_in[3];
    const float* df  = (const float*)d_in[4];
    const int* idxb  = (const int*)d_in[5];
    const int* clsb  = (const int*)d_in[6];
    const int* mining_p = (const int*)d_in[8];
    const int* slab  = (const int*)d_in[9];
    float* out = (float*)d_out;

    char* ws = (char*)d_ws;
    float* segacc     = (float*)ws;            // 4 B
    unsigned* done    = (unsigned*)(ws + 4);
    int*   np_i       = (int*)(ws + 64);       // 32 ints
    float* loc_i      = (float*)(ws + 192);    // 32 floats
    float* posce_i    = (float*)(ws + 320);    // 32 floats
    float* negce_i    = (float*)(ws + 448);    // 32 floats

    hipLaunchKernelGGL(k_front, dim3(BATCH), dim3(1024), 0, stream,
                       idxb, clsb, gt, df, Loc, Cls, mining_p,
                       loc_i, posce_i, negce_i, np_i, segacc, done);
    hipLaunchKernelGGL(k_seg, dim3(NBLK), dim3(256), 0, stream,
                       Seg, slab, segacc, np_i, loc_i, posce_i, negce_i, done, out);
}

// Round 3
// 124.525 us; speedup vs baseline: 1.2497x; 1.2497x over previous
//
#include <hip/hip_runtime.h>
#include <stdint.h>

#define BATCH 32
#define NA 8732
#define NC 21
#define SHW 90000
#define MAXGT 64
#define NQ (SHW / 4)          // 22500 pixel-quads per image per channel

// ---- k_seg geometry: 256 blocks (1/CU), 8 slabs/image, 2816 quads/slab ----
// Per channel a block DMAs ONE 45KB contiguous chunk into LDS and sweeps the
// 21 channels sequentially: 256 long forward streams chip-wide instead of the
// 1408-block x 21-stream x 8KB-nibble pattern (~30k streams) that ran at
// 1.8 TB/s (29% of achievable -- DRAM stream-locality thrash).
#define SPI 8                  // slabs per image
#define SQUADS 2816            // quads per slab (8*2816 = 22528 >= 22500)
#define QPT 11                 // quads per thread (2816 / 256)
#define WQ 704                 // quads per wave segment (2816 / 4 waves)
#define CHBF (SQUADS * 4)      // floats per channel chunk (45056 B)
#define CSTEP ((size_t)NQ * 16) // channel stride in bytes (360000)

__constant__ int c_loff[6] = {0, 5776, 7942, 8542, 8692, 8728};
__constant__ int c_lnb[6]  = {4, 6, 6, 6, 4, 4};

__device__ __forceinline__ unsigned f2key(float f) {
    unsigned u = __float_as_uint(f);
    return (u & 0x80000000u) ? ~u : (u | 0x80000000u);
}
__device__ __forceinline__ float key2f(unsigned k) {
    return __uint_as_float((k & 0x80000000u) ? (k ^ 0x80000000u) : ~k);
}

__global__ __launch_bounds__(64) void k_init(float* __restrict__ acc, int* __restrict__ npt,
                                             unsigned* __restrict__ done) {
    int t = threadIdx.x;
    if (t < 8) acc[t] = 0.0f;
    if (t == 8) *npt = 0;
    if (t == 9) *done = 0u;
}

// One block per image. Gather-style target build: for each anchor, find the
// LAST valid GT entry mapping to it (matches numpy last-write-wins scatter).
__global__ __launch_bounds__(1024) void k_build(
    const int* __restrict__ idxb, const int* __restrict__ clsb,
    const float* __restrict__ gt, const float* __restrict__ df,
    const float* __restrict__ Loc, const int* __restrict__ mining_p,
    signed char* __restrict__ cls_t, float* __restrict__ acc,
    int* __restrict__ num_pos_i, int* __restrict__ neg_cnt_i,
    int* __restrict__ npt)
{
    const int b = blockIdx.x;
    const int tid = threadIdx.x;
    __shared__ int s_flat[MAXGT];
    __shared__ int s_cls[MAXGT];
    __shared__ float s_delta[MAXGT][4];
    __shared__ int s_nv;
    __shared__ float s_wf[16];
    __shared__ int s_wp[16];
    __shared__ int s_wn[16];

    if (tid < MAXGT) {
        int layer = idxb[(b * MAXGT + tid) * 4 + 1];
        int fpos  = idxb[(b * MAXGT + tid) * 4 + 2];
        int dbox  = idxb[(b * MAXGT + tid) * 4 + 3];
        int fl;
        if (layer == -100) fl = -2;  // terminator sentinel
        else {
            int lc = min(max(layer, 0), 5);
            fl = c_loff[lc] + fpos * c_lnb[lc] + dbox;
        }
        s_flat[tid] = fl;
        s_cls[tid] = clsb[b * MAXGT + tid];
        #pragma unroll
        for (int o = 0; o < 4; o++)
            s_delta[tid][o] = (gt[(b * MAXGT + tid) * 4 + o] - df[(b * MAXGT + tid) * 4 + o]) / 0.1f;
    }
    __syncthreads();
    if (tid == 0) {
        int nv = MAXGT;
        for (int j = 0; j < MAXGT; j++) if (s_flat[j] == -2) { nv = j; break; }
        s_nv = nv;
    }
    __syncthreads();
    const int nv = s_nv;

    int rflat[MAXGT];
    #pragma unroll
    for (int j = 0; j < MAXGT; j++)
        rflat[j] = (j < nv) ? s_flat[j] : -3;

    const int mining = *mining_p;
    const signed char cinit = mining ? (signed char)(-1) : (signed char)0;
    int pos_cnt = 0, neg_cnt = 0;
    float loc_sum = 0.0f;

    for (int a = tid; a < NA; a += 1024) {
        int best = -1;
        #pragma unroll
        for (int j = 0; j < MAXGT; j++)
            best = (rflat[j] == a) ? j : best;   // last match wins
        signed char cv = cinit;
        if (best >= 0) cv = (signed char)s_cls[best];
        cls_t[b * NA + a] = cv;
        if (cv > 0) {
            pos_cnt++;
            const float4 l4 = *reinterpret_cast<const float4*>(Loc + ((size_t)b * NA + a) * 4);
            float lv[4] = {l4.x, l4.y, l4.z, l4.w};
            #pragma unroll
            for (int o = 0; o < 4; o++) {
                float d = lv[o] - s_delta[best][o];
                float ad = fabsf(d);
                loc_sum += (ad < 1.0f) ? (0.5f * d * d) : (ad - 0.5f);
            }
        } else if (cv == -1) {
            neg_cnt++;
        }
    }

    #pragma unroll
    for (int d = 32; d > 0; d >>= 1) {
        loc_sum += __shfl_down(loc_sum, d);
        pos_cnt += __shfl_down(pos_cnt, d);
        neg_cnt += __shfl_down(neg_cnt, d);
    }
    const int lane = tid & 63, wv = tid >> 6;
    if (lane == 0) { s_wf[wv] = loc_sum; s_wp[wv] = pos_cnt; s_wn[wv] = neg_cnt; }
    __syncthreads();
    if (tid == 0) {
        float lf = 0.0f; int pp = 0, nn = 0;
        #pragma unroll
        for (int w = 0; w < 16; w++) { lf += s_wf[w]; pp += s_wp[w]; nn += s_wn[w]; }
        atomicAdd(acc + 2, lf);
        num_pos_i[b] = pp;
        atomicAdd(npt, pp);
        neg_cnt_i[b] = nn;
    }
}

// 256 rows per block, staged to LDS via 6 coalesced float4 rounds (one
// sequential 21.5KB stream per block), then per-thread logsumexp from LDS.
__global__ __launch_bounds__(256) void k_cls(
    const float* __restrict__ Cls, const signed char* __restrict__ cls_t,
    const int* __restrict__ mining_p, float* __restrict__ scores,
    float* __restrict__ acc)
{
    __shared__ __align__(16) float s_c[256 * NC];  // 21504 B
    __shared__ float s_wp[4];
    __shared__ float s_wn[4];
    const int t = threadIdx.x;
    const size_t base = (size_t)blockIdx.x * (256 * NC);
    const size_t total = (size_t)BATCH * NA * NC;
    const int nchunks = (int)((total - base) >> 2) < (256 * NC / 4)
                        ? (int)((total - base) >> 2) : (256 * NC / 4);
    #pragma unroll
    for (int k = 0; k < 6; k++) {
        int j4 = t + k * 256;
        if (j4 < nchunks) {
            *reinterpret_cast<float4*>(&s_c[j4 * 4]) =
                *reinterpret_cast<const float4*>(Cls + base + (size_t)j4 * 4);
        }
    }
    __syncthreads();

    const int r = blockIdx.x * 256 + t;
    const int mining = *mining_p;
    float pos_ce = 0.0f, neg_ce = 0.0f;
    if (r < BATCH * NA) {
        float f[NC];
        #pragma unroll
        for (int c = 0; c < NC; c++) f[c] = s_c[t * NC + c];
        float m = f[0];
        #pragma unroll
        for (int c = 1; c < NC; c++) m = fmaxf(m, f[c]);
        float s = 0.0f;
        #pragma unroll
        for (int c = 0; c < NC; c++) s += __expf(f[c] - m);
        float lse = m + __logf(s);
        int ct = (int)cls_t[r];
        int lab = ct > 0 ? ct : 0;
        float xt = f[0];
        #pragma unroll
        for (int c = 1; c < NC; c++) xt = (c == lab) ? f[c] : xt;
        float ce_bg = lse - f[0];
        if (ct > 0) pos_ce = lse - xt;
        if (mining) {
            scores[r] = (ct == -1) ? ce_bg : -__builtin_inff();
        } else if (ct <= 0) {
            neg_ce = ce_bg;
        }
    }
    #pragma unroll
    for (int d = 32; d > 0; d >>= 1) {
        pos_ce += __shfl_down(pos_ce, d);
        neg_ce += __shfl_down(neg_ce, d);
    }
    const int lane = t & 63, wv = t >> 6;
    if (lane == 0) { s_wp[wv] = pos_ce; s_wn[wv] = neg_ce; }
    __syncthreads();
    if (t == 0) {
        float p = s_wp[0] + s_wp[1] + s_wp[2] + s_wp[3];
        float n = s_wn[0] + s_wn[1] + s_wn[2] + s_wn[3];
        if (p != 0.0f) atomicAdd(acc + 0, p);
        if (n != 0.0f) atomicAdd(acc + 1, n);
    }
}

// One block per image: exact top-k via 4-round (8-bit) LDS radix select.
__global__ __launch_bounds__(256) void k_topk(
    const float* __restrict__ scores, const int* __restrict__ num_pos_i,
    const int* __restrict__ neg_cnt_i, const int* __restrict__ mining_p,
    float* __restrict__ acc)
{
    if (*mining_p == 0) return;
    const int b = blockIdx.x;
    const int tid = threadIdx.x;
    const int k = min(3 * num_pos_i[b], neg_cnt_i[b]);
    if (k <= 0) return;

    __shared__ unsigned s_keys[NA];
    __shared__ int s_hist[256];
    __shared__ int s_wsum[4];
    __shared__ int s_selb;
    __shared__ int s_sele;
    __shared__ float s_wf[4];
    __shared__ int s_wc[4];

    const float* sc = scores + (size_t)b * NA;
    for (int a = tid; a < NA; a += 256)
        s_keys[a] = f2key(sc[a]);

    const int lane = tid & 63, wv = tid >> 6;
    unsigned pref = 0u;
    int k_rem = k;

    #pragma unroll
    for (int lvl = 0; lvl < 4; lvl++) {
        const int sh = 24 - lvl * 8;
        s_hist[tid] = 0;
        __syncthreads();
        for (int a = tid; a < NA; a += 256) {
            unsigned key = s_keys[a];
            bool in = (lvl == 0) || ((key >> (sh + 8)) == pref);
            if (in) atomicAdd(&s_hist[(key >> sh) & 0xFF], 1);
        }
        __syncthreads();
        const int b_rev = 255 - tid;
        const int v = s_hist[b_rev];
        int x = v;
        #pragma unroll
        for (int d = 1; d < 64; d <<= 1) {
            int o = __shfl_up(x, d);
            if (lane >= d) x += o;
        }
        if (lane == 63) s_wsum[wv] = x;
        __syncthreads();
        for (int w = 0; w < wv; w++) x += s_wsum[w];
        if (x >= k_rem && (x - v) < k_rem) { s_selb = b_rev; s_sele = x - v; }
        __syncthreads();
        pref = (pref << 8) | (unsigned)s_selb;
        k_rem -= s_sele;
        __syncthreads();
    }

    float sum_g = 0.0f; int cnt_g = 0;
    for (int a = tid; a < NA; a += 256) {
        unsigned key = s_keys[a];
        if (key > pref) { sum_g += key2f(key); cnt_g++; }
    }
    #pragma unroll
    for (int d = 32; d > 0; d >>= 1) {
        sum_g += __shfl_down(sum_g, d);
        cnt_g += __shfl_down(cnt_g, d);
    }
    if (lane == 0) { s_wf[wv] = sum_g; s_wc[wv] = cnt_g; }
    __syncthreads();
    if (tid == 0) {
        float sg = s_wf[0] + s_wf[1] + s_wf[2] + s_wf[3];
        int cg = s_wc[0] + s_wc[1] + s_wc[2] + s_wc[3];
        atomicAdd(acc + 1, sg + (float)(k - cg) * key2f(pref));
    }
}

// ============================================================================
// k_seg: channel-sweep streaming CE. LDS triple-buffer staging via
// global_load_lds (spill-proof: no in-flight asm register destinations).
// ============================================================================

// Online-LSE update, 1 transcendental per element (bit-identical to 2-exp
// form, verified absmax 0.0 in prior rounds).
__device__ __forceinline__ void upd1(float& m, float& s, float& tg,
                                     int lab, float x, int c) {
    tg = (lab == c) ? x : tg;
    const float d = x - m;
    const float e = __expf(-fabsf(d));
    s = (d > 0.0f) ? fmaf(s, e, 1.0f) : (s + e);
    m = fmaxf(m, x);
}
__device__ __forceinline__ void upd4p(float4& m, float4& s, float4& tg,
                                      unsigned lp, const float4& x, int c) {
    upd1(m.x, s.x, tg.x, (int)(lp & 0xFFu),         x.x, c);
    upd1(m.y, s.y, tg.y, (int)((lp >> 8) & 0xFFu),  x.y, c);
    upd1(m.z, s.z, tg.z, (int)((lp >> 16) & 0xFFu), x.z, c);
    upd1(m.w, s.w, tg.w, (int)((lp >> 24) & 0xFFu), x.w, c);
}

#define GLOAD_I4(dst, addr) \
    asm volatile("global_load_dwordx4 %0, %1, off" : "=v"(dst) : "v"(addr))
// rule #18: sched_barrier(0) after the wait so consumers can't hoist above it.
#define SWAIT(lit) do { \
    asm volatile("s_waitcnt vmcnt(" #lit ")" ::: "memory"); \
    __builtin_amdgcn_sched_barrier(0); } while (0)

// Stage one 45KB channel chunk: wave w DMAs its 11264-B segment in 11 1-KB
// issues. LDS dest = wave-uniform base + lane*16 (the HW constraint); global
// source is per-lane (clamped at the slab tail to quad NQ-1, excluded later).
__device__ __forceinline__ void stage_chan(const char* segbase, int c,
                                           float* ldswave, const uint32_t* boff) {
    const char* cb = segbase + (size_t)c * CSTEP;
    #pragma unroll
    for (int i = 0; i < QPT; i++) {
        __builtin_amdgcn_global_load_lds(
            (__attribute__((address_space(1))) void*)(cb + boff[i]),
            (__attribute__((address_space(3))) void*)(ldswave + i * 256),
            16, 0, 0);
    }
}

// Raw barrier (no implicit vmcnt(0) drain -- __syncthreads would kill the
// 2-channel-ahead DMA pipeline). sched_barrier fences both sides.
#define RBAR() do { \
    __builtin_amdgcn_sched_barrier(0); \
    __builtin_amdgcn_s_barrier(); \
    __builtin_amdgcn_sched_barrier(0); } while (0)

__global__ __launch_bounds__(256, 1) void k_seg(
    const float* __restrict__ Seg, const int* __restrict__ slab_lab,
    float* __restrict__ acc, const int* __restrict__ npt,
    unsigned* __restrict__ done, float* __restrict__ out)
{
    __shared__ __align__(16) float s_buf[3 * CHBF];   // 3 x 45056 B = 135168 B
    __shared__ float s_w[4];
    const int t = threadIdx.x;
    const int lane = t & 63, w = t >> 6;
    const int img = blockIdx.x >> 3;
    const int sl  = blockIdx.x & 7;
    const int qbase = sl * SQUADS;

    const char* segbase = (const char*)(Seg + (size_t)img * NC * SHW);
    const char* labbase = (const char*)(slab_lab + (size_t)img * SHW);

    // ---- labels: asm-pinned loads, fully drained BEFORE any DMA so the
    // counted vmcnt waits below track only global_load_lds issues ----
    int4 la[QPT];
    #pragma unroll
    for (int k = 0; k < QPT; k++) {
        int q = qbase + t + k * 256;
        int qc = (q < NQ) ? q : (NQ - 1);
        GLOAD_I4(la[k], (uint64_t)labbase + (uint64_t)qc * 16u);
    }
    SWAIT(0);
    unsigned lp[QPT];   // labels 0..20: pack to u8x4 (frees 33 VGPRs)
    #pragma unroll
    for (int k = 0; k < QPT; k++)
        lp[k] = ((unsigned)la[k].x & 0xFFu) | (((unsigned)la[k].y & 0xFFu) << 8)
              | (((unsigned)la[k].z & 0xFFu) << 16) | (((unsigned)la[k].w & 0xFFu) << 24);

    // per-lane channel-invariant global byte offsets for the DMA issues
    uint32_t boff[QPT];
    #pragma unroll
    for (int i = 0; i < QPT; i++) {
        int qg = qbase + w * WQ + i * 64 + lane;
        int qc = (qg < NQ) ? qg : (NQ - 1);
        boff[i] = (uint32_t)qc * 16u;
    }
    float* ldsw0 = s_buf + (size_t)w * (WQ * 4);   // wave's segment in buffer 0

    float4 m4[QPT], s4[QPT], t4[QPT];

    // ---- prologue: stage c=0,c=1; compute c=0 (init); keep c+1 in flight ----
    stage_chan(segbase, 0, ldsw0, boff);
    stage_chan(segbase, 1, ldsw0 + CHBF, boff);
    SWAIT(11);          // my c0 DMAs done; c1's 11 stay in flight
    RBAR();             // all waves' c0 DMAs done
    stage_chan(segbase, 2, ldsw0 + 2 * CHBF, boff);
    #pragma unroll
    for (int k = 0; k < QPT; k++) {
        float4 x = *reinterpret_cast<const float4*>(s_buf + (size_t)(t + k * 256) * 4);
        m4[k] = x; t4[k] = x;
        s4[k] = make_float4(1.f, 1.f, 1.f, 1.f);
    }

    // ---- steady: one barrier per channel; buffer (c+2)%3 was last read at
    // channel c-1, and the top-of-iter barrier proves everyone finished it ----
    #pragma unroll 1
    for (int c = 1; c < NC; ++c) {
        if (c == NC - 1) SWAIT(0); else SWAIT(11);
        RBAR();
        if (c + 2 < NC) stage_chan(segbase, c + 2, ldsw0 + ((c + 2) % 3) * CHBF, boff);
        const float* bp = s_buf + (size_t)(c % 3) * CHBF;
        #pragma unroll
        for (int k = 0; k < QPT; k++) {
            float4 x = *reinterpret_cast<const float4*>(bp + (size_t)(t + k * 256) * 4);
            upd4p(m4[k], s4[k], t4[k], lp[k], x, c);
        }
    }

    float lsum = 0.0f;
    #pragma unroll
    for (int k = 0; k < QPT; k++) {
        int q = qbase + t + k * 256;
        if (q < NQ) {
            lsum += (m4[k].x + __logf(s4[k].x) - t4[k].x)
                  + (m4[k].y + __logf(s4[k].y) - t4[k].y)
                  + (m4[k].z + __logf(s4[k].z) - t4[k].z)
                  + (m4[k].w + __logf(s4[k].w) - t4[k].w);
        }
    }

    #pragma unroll
    for (int d = 32; d > 0; d >>= 1) lsum += __shfl_down(lsum, d);
    if (lane == 0) s_w[w] = lsum;
    __syncthreads();
    if (t == 0) {
        atomicAdd(acc + 3, s_w[0] + s_w[1] + s_w[2] + s_w[3]);
        __threadfence();
        unsigned old = atomicAdd(done, 1u);
        if (old == gridDim.x - 1) {
            __threadfence();
            int np_i = *npt;
            float np = (float)(np_i > 1 ? np_i : 1);
            out[0] = (acc[0] + acc[1] + acc[2]) / np
                   + acc[3] / (float)(BATCH * SHW);
        }
    }
}

extern "C" void kernel_launch(void* const* d_in, const int* in_sizes, int n_in,
                              void* d_out, int out_size, void* d_ws, size_t ws_size,
                              hipStream_t stream)
{
    const float* Loc = (const float*)d_in[0];
    const float* Cls = (const float*)d_in[1];
    const float* Seg = (const float*)d_in[2];
    const float* gt  = (const float*)d_in[3];
    const float* df  = (const float*)d_in[4];
    const int* idxb  = (const int*)d_in[5];
    const int* clsb  = (const int*)d_in[6];
    const int* mining_p = (const int*)d_in[8];
    const int* slab  = (const int*)d_in[9];
    float* out = (float*)d_out;

    char* ws = (char*)d_ws;
    float* acc        = (float*)ws;            // 8 floats
    int*   npt        = (int*)(ws + 32);
    unsigned* done    = (unsigned*)(ws + 36);
    int*   num_pos_i  = (int*)(ws + 64);       // 32 ints
    int*   neg_cnt_i  = (int*)(ws + 192);      // 32 ints
    signed char* cls_t = (signed char*)(ws + 512);          // BATCH*NA bytes
    float* scores      = (float*)(ws + 512 + 279424);       // BATCH*NA floats

    hipLaunchKernelGGL(k_init, dim3(1), dim3(64), 0, stream, acc, npt, done);
    hipLaunchKernelGGL(k_build, dim3(BATCH), dim3(1024), 0, stream,
                       idxb, clsb, gt, df, Loc, mining_p, cls_t, acc, num_pos_i, neg_cnt_i, npt);
    hipLaunchKernelGGL(k_cls, dim3((BATCH * NA + 255) / 256), dim3(256), 0, stream,
                       Cls, cls_t, mining_p, scores, acc);
    hipLaunchKernelGGL(k_topk, dim3(BATCH), dim3(256), 0, stream,
                       scores, num_pos_i, neg_cnt_i, mining_p, acc);
    hipLaunchKernelGGL(k_seg, dim3(BATCH * SPI), dim3(256), 0, stream,
                       Seg, slab, acc, npt, done, out);
}